// Round 2
// baseline (153.511 us; speedup 1.0000x reference)
//
#include <hip/hip_runtime.h>
#include <hip/hip_bf16.h>

// Q3 unpack: each int32 holds 10 x 3-bit fields at shifts 27,24,...,0.
// Output block k (k=0..9) along dim 0 is ((packed >> (27-3k)) & 7).
// Harness stores integer outputs as int32 -> write int32 values 0..7.

__global__ __launch_bounds__(256) void q3_unpack_kernel(
    const int4* __restrict__ in, int4* __restrict__ out, int nvec, int block_stride_vec) {
    int i = blockIdx.x * blockDim.x + threadIdx.x;
    if (i >= nvec) return;
    int4 p = in[i];
#pragma unroll
    for (int k = 0; k < 10; ++k) {
        const int sh = 27 - 3 * k;
        int4 v;
        v.x = (p.x >> sh) & 7;
        v.y = (p.y >> sh) & 7;
        v.z = (p.z >> sh) & 7;
        v.w = (p.w >> sh) & 7;
        out[(size_t)k * (size_t)block_stride_vec + (size_t)i] = v;
    }
}

extern "C" void kernel_launch(void* const* d_in, const int* in_sizes, int n_in,
                              void* d_out, int out_size, void* d_ws, size_t ws_size,
                              hipStream_t stream) {
    const int* packed = (const int*)d_in[0];
    int* out = (int*)d_out;

    const int n_words = in_sizes[0];          // 4096*4096 = 16,777,216
    const int nvec = n_words / 4;             // int4 count = 4,194,304
    const int block_stride_vec = n_words / 4; // each k-block is n_words ints = n_words/4 int4

    const int threads = 256;
    const int blocks = (nvec + threads - 1) / threads;

    q3_unpack_kernel<<<blocks, threads, 0, stream>>>(
        (const int4*)packed, (int4*)out, nvec, block_stride_vec);
}